// Round 7
// baseline (107.323 us; speedup 1.0000x reference)
//
#include <hip/hip_runtime.h>
#include <hip/hip_bf16.h>
#include <stdint.h>

#define B_DIM 16384
#define H_DIM 512
#define KTOT  1024   // I + H
#define NP    2048   // 4 gates * H

typedef __attribute__((ext_vector_type(8))) short short8;
typedef __attribute__((ext_vector_type(4))) float floatx4;

static __device__ __forceinline__ unsigned short f2bf(float f) {
  unsigned int u = __float_as_uint(f);
  u += 0x7fffu + ((u >> 16) & 1u);
  return (unsigned short)(u >> 16);
}

static __device__ __forceinline__ short8 cvt8(floatx4 v0, floatx4 v1) {
  short8 o;
#pragma unroll
  for (int i = 0; i < 4; ++i) {
    o[i]     = (short)f2bf(v0[i]);
    o[i + 4] = (short)f2bf(v1[i]);
  }
  return o;
}

// ---------------------------------------------------------------------------
// Packed A (bf16), 16x16x32 frag-linear, BK=32 tiles (same as R6):
//   [bm(64)][kt(32)][wr(2)][mh(2)][m4(4)][lane(64)][j(8)]
//   row = bm*256 + wr*128 + mh*64 + m4*16 + (lane&15)
//   k   = kt*32 + (lane>>4)*8 + j          (k<512 -> x, else z)
// ---------------------------------------------------------------------------
__global__ __launch_bounds__(256) void pack_a_kernel(
    const float* __restrict__ x, const float* __restrict__ z,
    unsigned short* __restrict__ Ap) {
  int u    = blockIdx.x * 256 + threadIdx.x;
  int lane = u & 63;
  int m4   = (u >> 6) & 3;
  int mh   = (u >> 8) & 1;
  int wr   = (u >> 9) & 1;
  int kt   = (u >> 10) & 31;
  int bm   = u >> 15;
  int row  = bm * 256 + wr * 128 + mh * 64 + m4 * 16 + (lane & 15);
  int k    = kt * 32 + ((lane >> 4) << 3);
  const float* src = (k < 512) ? (x + (uint64_t)row * 512 + k)
                               : (z + (uint64_t)row * 512 + (k - 512));
  floatx4 v0 = *reinterpret_cast<const floatx4*>(src);
  floatx4 v1 = *reinterpret_cast<const floatx4*>(src + 4);
  *reinterpret_cast<short8*>(Ap + (uint64_t)u * 8) = cvt8(v0, v1);
}

// ---------------------------------------------------------------------------
// Packed B (bf16), gate-major frags, BK=32 tiles (same as R6):
//   [bn(8)][kt(32)][wc(4)][nh(2)][n2(2)][lane(64)][j(8)]
//   h = bn*64 + wc*16 + (lane&15); gate g = nh*2+n2
//   k = kt*32 + (lane>>4)*8 + j            (k<512 -> W_g, else U_g)
// ---------------------------------------------------------------------------
__global__ __launch_bounds__(256) void pack_w_kernel(
    const float* __restrict__ Wi, const float* __restrict__ Wf,
    const float* __restrict__ Wc, const float* __restrict__ Wo,
    const float* __restrict__ Ui, const float* __restrict__ Uf,
    const float* __restrict__ Uc, const float* __restrict__ Uo,
    unsigned short* __restrict__ Bp) {
  int u    = blockIdx.x * 256 + threadIdx.x;
  int lane = u & 63;
  int n2   = (u >> 6) & 1;
  int nh   = (u >> 7) & 1;
  int wc   = (u >> 8) & 3;
  int kt   = (u >> 10) & 31;
  int bn   = u >> 15;
  int g    = nh * 2 + n2;
  int h    = bn * 64 + wc * 16 + (lane & 15);
  int k    = kt * 32 + ((lane >> 4) << 3);
  const float* src;
  if (k < 512) {
    const float* W = (g == 0) ? Wi : (g == 1) ? Wf : (g == 2) ? Wc : Wo;
    src = W + (uint64_t)h * 512 + k;
  } else {
    const float* U = (g == 0) ? Ui : (g == 1) ? Uf : (g == 2) ? Uc : Uo;
    src = U + (uint64_t)h * 512 + (k - 512);
  }
  floatx4 v0 = *reinterpret_cast<const floatx4*>(src);
  floatx4 v1 = *reinterpret_cast<const floatx4*>(src + 4);
  *reinterpret_cast<short8*>(Bp + (uint64_t)u * 8) = cvt8(v0, v1);
}

// stage one 16KB tile image: 512 threads x 16B x 2 instructions
static __device__ __forceinline__ void stage2(const unsigned short* g,
                                              unsigned short* l, int tid) {
  __builtin_amdgcn_global_load_lds(
      (const __attribute__((address_space(1))) void*)(g + tid * 8),
      (__attribute__((address_space(3))) void*)(l + tid * 8), 16, 0, 0);
  __builtin_amdgcn_global_load_lds(
      (const __attribute__((address_space(1))) void*)(g + 4096 + tid * 8),
      (__attribute__((address_space(3))) void*)(l + 4096 + tid * 8), 16, 0, 0);
}

// m201 phase skeleton: [reads + stage] -> barrier -> lgkmcnt(0) -> fenced
// pure-MFMA setprio cluster -> [optional vmcnt] -> barrier
#define PH_ENTER                                                            \
  __builtin_amdgcn_s_barrier();                                             \
  asm volatile("s_waitcnt lgkmcnt(0)" ::: "memory");                        \
  __builtin_amdgcn_sched_barrier(0);
#define PH_MFMA(MB)                                                         \
  __builtin_amdgcn_s_setprio(1);                                            \
  _Pragma("unroll")                                                         \
  for (int m4 = 0; m4 < 4; ++m4)                                            \
    _Pragma("unroll")                                                       \
    for (int g = 0; g < 4; ++g)                                             \
      acc[(MB) + m4][g] = __builtin_amdgcn_mfma_f32_16x16x32_bf16(          \
          aF[m4], bF[g], acc[(MB) + m4][g], 0, 0, 0);                       \
  __builtin_amdgcn_s_setprio(0);                                            \
  __builtin_amdgcn_sched_barrier(0);
#define RD_B                                                                \
  _Pragma("unroll")                                                         \
  for (int g = 0; g < 4; ++g)                                               \
    bF[g] = *reinterpret_cast<const short8*>(bC + g * 512);
#define RD_A(OFF)                                                           \
  _Pragma("unroll")                                                         \
  for (int m4 = 0; m4 < 4; ++m4)                                            \
    aF[m4] = *reinterpret_cast<const short8*>(aC + (OFF) + m4 * 512);

// ---------------------------------------------------------------------------
// GEMM M=16384 Np=2048 K=1024. Tile 256x256, BK=32, 8 waves (2wr x 4wc),
// wave = 128x64 (16h x 4 gates), acc[8][4] = 128 AGPR.
// m201-faithful schedule: 2 phases per K-tile (mh=0: 8 reads + 16 MFMA,
// mh=1: 4 reads + 16 MFMA), two barriers per phase, lgkmcnt(0) only before
// the cluster, ONE counted vmcnt(4) per tile (never draining: the 4 newest
// loads = tile kt+2 stay in flight), vmcnt(0) only at tile 30.
// LDS = ring of 4 x 32KB (128KB): read buf kt&3, write buf (kt+2)&3.
// ---------------------------------------------------------------------------
__global__ __launch_bounds__(512, 2) void lstm_gemm_kernel(
    const unsigned short* __restrict__ Ap,
    const unsigned short* __restrict__ Bp,
    const float* __restrict__ z,
    const float* __restrict__ b_i, const float* __restrict__ b_f,
    const float* __restrict__ b_c, const float* __restrict__ b_o,
    float* __restrict__ out) {
  __shared__ unsigned short lds[65536];  // 128KB = 4 bufs x (A 16KB | B 16KB)

  int tid  = threadIdx.x;
  int bid  = blockIdx.x;
  int sw   = (bid & 7) * 64 + (bid >> 3);  // 512 % 8 == 0 -> bijective
  int bn   = sw & 7;     // 8 N-tiles (64 h * 4 gates)
  int bm   = sw >> 3;    // 64 M-tiles
  int lane = tid & 63;
  int wid  = tid >> 6;
  int wr   = wid >> 2;   // 0..1 -> 128 rows
  int wc   = wid & 3;    // 0..3 -> 16 h * 4 gates

  floatx4 acc[8][4];
#pragma unroll
  for (int m = 0; m < 8; ++m)
#pragma unroll
    for (int g = 0; g < 4; ++g)
      acc[m][g] = (floatx4){0.f, 0.f, 0.f, 0.f};

  const unsigned short* gA = Ap + (uint64_t)bm * (32 * 8192);
  const unsigned short* gB = Bp + (uint64_t)bn * (32 * 8192);

  // prologue: stage tiles 0 (buf0) and 1 (buf1); wait tile0 -> vmcnt(4)
  stage2(gA, lds, tid);
  stage2(gB, lds + 8192, tid);
  stage2(gA + 8192, lds + 16384, tid);
  stage2(gB + 8192, lds + 16384 + 8192, tid);
  asm volatile("s_waitcnt vmcnt(4)" ::: "memory");
  __builtin_amdgcn_sched_barrier(0);
  __builtin_amdgcn_s_barrier();
  __builtin_amdgcn_sched_barrier(0);

  short8 aF[4], bF[4];

#pragma unroll 1
  for (int kt = 0; kt < 30; ++kt) {
    const int cur = (kt & 3) * 16384;
    const int nxt = ((kt + 2) & 3) * 16384;
    const unsigned short* aC = lds + cur + wr * 4096 + lane * 8;
    const unsigned short* bC = lds + cur + 8192 + wc * 2048 + lane * 8;
    const unsigned short* gAs = gA + (kt + 2) * 8192;
    const unsigned short* gBs = gB + (kt + 2) * 8192;

    // phase 0 (mh=0): 8 reads + stage A(kt+2)
    RD_B RD_A(0)
    stage2(gAs, lds + nxt, tid);
    PH_ENTER
    PH_MFMA(0)
    __builtin_amdgcn_s_barrier();
    __builtin_amdgcn_sched_barrier(0);

    // phase 1 (mh=1): 4 reads (B reused) + stage B(kt+2)
    RD_A(2048)
    stage2(gBs, lds + nxt + 8192, tid);
    PH_ENTER
    PH_MFMA(4)
    asm volatile("s_waitcnt vmcnt(4)" ::: "memory");  // kt+1 landed; kt+2 in flight
    __builtin_amdgcn_sched_barrier(0);
    __builtin_amdgcn_s_barrier();
    __builtin_amdgcn_sched_barrier(0);
  }

  // tile 30: no staging; drain so tile 31 is fully landed
  {
    const int cur = (30 & 3) * 16384;
    const unsigned short* aC = lds + cur + wr * 4096 + lane * 8;
    const unsigned short* bC = lds + cur + 8192 + wc * 2048 + lane * 8;
    RD_B RD_A(0)
    PH_ENTER
    PH_MFMA(0)
    __builtin_amdgcn_s_barrier();
    __builtin_amdgcn_sched_barrier(0);
    RD_A(2048)
    PH_ENTER
    PH_MFMA(4)
    asm volatile("s_waitcnt vmcnt(0)" ::: "memory");
    __builtin_amdgcn_sched_barrier(0);
    __builtin_amdgcn_s_barrier();
    __builtin_amdgcn_sched_barrier(0);
  }
  // tile 31: last
  {
    const int cur = (31 & 3) * 16384;
    const unsigned short* aC = lds + cur + wr * 4096 + lane * 8;
    const unsigned short* bC = lds + cur + 8192 + wc * 2048 + lane * 8;
    RD_B RD_A(0)
    PH_ENTER
    PH_MFMA(0)
    __builtin_amdgcn_s_barrier();
    __builtin_amdgcn_sched_barrier(0);
    RD_A(2048)
    PH_ENTER
    PH_MFMA(4)
  }

  // ---- fused LSTM epilogue (lane-local: acc frag index g == gate)
  int h = bn * 64 + wc * 16 + (lane & 15);
  float vbi = b_i[h], vbf = b_f[h], vbc = b_c[h], vbo = b_o[h];
  int rbase = bm * 256 + wr * 128 + ((lane >> 4) << 2);
  float* outH = out;
  float* outC = out + (uint64_t)B_DIM * H_DIM;
#pragma unroll
  for (int m = 0; m < 8; ++m) {
#pragma unroll
    for (int j = 0; j < 4; ++j) {
      int r = rbase + m * 16 + j;
      float pi = acc[m][0][j] + vbi;
      float pf = acc[m][1][j] + vbf;
      float pc = acc[m][2][j] + vbc;
      float po = acc[m][3][j] + vbo;
      float gi = 1.f / (1.f + __expf(-pi));
      float gf = 1.f / (1.f + __expf(-pf));
      float gc = 1.f - 2.f / (__expf(2.f * pc) + 1.f);  // tanh
      float go = 1.f / (1.f + __expf(-po));
      float zv = z[(uint64_t)r * H_DIM + h];
      float cn = gf * zv + gi * gc;
      float hn = go * (1.f - 2.f / (__expf(2.f * cn) + 1.f));
      outH[(uint64_t)r * H_DIM + h] = hn;
      outC[(uint64_t)r * H_DIM + h] = cn;
    }
  }
}

extern "C" void kernel_launch(void* const* d_in, const int* in_sizes, int n_in,
                              void* d_out, int out_size, void* d_ws, size_t ws_size,
                              hipStream_t stream) {
  const float* z  = (const float*)d_in[0];
  const float* x  = (const float*)d_in[1];
  const float* Wi = (const float*)d_in[2];
  const float* Wf = (const float*)d_in[3];
  const float* Wc = (const float*)d_in[4];
  const float* Wo = (const float*)d_in[5];
  const float* bi = (const float*)d_in[6];
  const float* bf = (const float*)d_in[7];
  const float* bc = (const float*)d_in[8];
  const float* bo = (const float*)d_in[9];
  const float* Ui = (const float*)d_in[10];
  const float* Uf = (const float*)d_in[11];
  const float* Uc = (const float*)d_in[12];
  const float* Uo = (const float*)d_in[13];

  unsigned short* Ap = (unsigned short*)d_ws;                          // 32 MB
  unsigned short* Bp = (unsigned short*)((char*)d_ws
                        + (size_t)B_DIM * KTOT * sizeof(unsigned short)); // +4 MB
  float* out = (float*)d_out;

  hipLaunchKernelGGL(pack_w_kernel, dim3((size_t)NP * KTOT / 8 / 256), dim3(256), 0, stream,
                     Wi, Wf, Wc, Wo, Ui, Uf, Uc, Uo, Bp);
  hipLaunchKernelGGL(pack_a_kernel, dim3((size_t)B_DIM * KTOT / 8 / 256), dim3(256), 0, stream,
                     x, z, Ap);
  hipLaunchKernelGGL(lstm_gemm_kernel, dim3(512), dim3(512), 0, stream,
                     Ap, Bp, z, bi, bf, bc, bo, out);
}

// Round 8
// 101.375 us; speedup vs baseline: 1.0587x; 1.0587x over previous
//
#include <hip/hip_runtime.h>
#include <hip/hip_bf16.h>
#include <stdint.h>

#define B_DIM 16384
#define H_DIM 512
#define KTOT  1024   // I + H
#define NP    2048   // 4 gates * H

typedef __attribute__((ext_vector_type(8))) short short8;
typedef __attribute__((ext_vector_type(4))) float floatx4;

static __device__ __forceinline__ unsigned short f2bf(float f) {
  unsigned int u = __float_as_uint(f);
  u += 0x7fffu + ((u >> 16) & 1u);
  return (unsigned short)(u >> 16);
}

static __device__ __forceinline__ short8 cvt8(floatx4 v0, floatx4 v1) {
  short8 o;
#pragma unroll
  for (int i = 0; i < 4; ++i) {
    o[i]     = (short)f2bf(v0[i]);
    o[i + 4] = (short)f2bf(v1[i]);
  }
  return o;
}

// ---------------------------------------------------------------------------
// Packed A (bf16), 16x16x32 frag-linear, BK=32 tiles (unchanged from R6):
//   [bm(64)][kt(32)][wr(2)][mh(2)][m4(4)][lane(64)][j(8)]
//   row = bm*256 + wr*128 + mh*64 + m4*16 + (lane&15)
//   k   = kt*32 + (lane>>4)*8 + j          (k<512 -> x, else z)
// Tile (bm,kt) = 8192 ushorts = 16KB = exact LDS A-tile image.
// ---------------------------------------------------------------------------
__global__ __launch_bounds__(256) void pack_a_kernel(
    const float* __restrict__ x, const float* __restrict__ z,
    unsigned short* __restrict__ Ap) {
  int u    = blockIdx.x * 256 + threadIdx.x;
  int lane = u & 63;
  int m4   = (u >> 6) & 3;
  int mh   = (u >> 8) & 1;
  int wr   = (u >> 9) & 1;
  int kt   = (u >> 10) & 31;
  int bm   = u >> 15;
  int row  = bm * 256 + wr * 128 + mh * 64 + m4 * 16 + (lane & 15);
  int k    = kt * 32 + ((lane >> 4) << 3);
  const float* src = (k < 512) ? (x + (uint64_t)row * 512 + k)
                               : (z + (uint64_t)row * 512 + (k - 512));
  floatx4 v0 = *reinterpret_cast<const floatx4*>(src);
  floatx4 v1 = *reinterpret_cast<const floatx4*>(src + 4);
  *reinterpret_cast<short8*>(Ap + (uint64_t)u * 8) = cvt8(v0, v1);
}

// ---------------------------------------------------------------------------
// Packed B (bf16), gate-major frags, BK=32, BN=128 tiles:
//   unit u = (bn*32 + kt)*512 + wc*256 + g*64 + lane
//   h = bn*32 + wc*16 + (lane&15); gate g; k = kt*32 + (lane>>4)*8 + j
// Tile (bn,kt) = 4096 ushorts = 8KB = exact LDS B-tile image.
// ---------------------------------------------------------------------------
__global__ __launch_bounds__(256) void pack_w_kernel(
    const float* __restrict__ Wi, const float* __restrict__ Wf,
    const float* __restrict__ Wc, const float* __restrict__ Wo,
    const float* __restrict__ Ui, const float* __restrict__ Uf,
    const float* __restrict__ Uc, const float* __restrict__ Uo,
    unsigned short* __restrict__ Bp) {
  int u    = blockIdx.x * 256 + threadIdx.x;
  int lane = u & 63;
  int g    = (u >> 6) & 3;
  int wc   = (u >> 8) & 1;
  int kt   = (u >> 9) & 31;
  int bn   = u >> 14;
  int h    = bn * 32 + wc * 16 + (lane & 15);
  int k    = kt * 32 + ((lane >> 4) << 3);
  const float* src;
  if (k < 512) {
    const float* W = (g == 0) ? Wi : (g == 1) ? Wf : (g == 2) ? Wc : Wo;
    src = W + (uint64_t)h * 512 + k;
  } else {
    const float* U = (g == 0) ? Ui : (g == 1) ? Uf : (g == 2) ? Uc : Uo;
    src = U + (uint64_t)h * 512 + (k - 512);
  }
  floatx4 v0 = *reinterpret_cast<const floatx4*>(src);
  floatx4 v1 = *reinterpret_cast<const floatx4*>(src + 4);
  *reinterpret_cast<short8*>(Bp + (uint64_t)u * 8) = cvt8(v0, v1);
}

// stage A-tile (16KB): 256 thr x 16B x 4 instrs; B-tile (8KB): x 2
static __device__ __forceinline__ void stageA(const unsigned short* g,
                                              unsigned short* l, int tid) {
#pragma unroll
  for (int r = 0; r < 4; ++r)
    __builtin_amdgcn_global_load_lds(
        (const __attribute__((address_space(1))) void*)(g + r * 2048 + tid * 8),
        (__attribute__((address_space(3))) void*)(l + r * 2048 + tid * 8), 16, 0, 0);
}
static __device__ __forceinline__ void stageB(const unsigned short* g,
                                              unsigned short* l, int tid) {
#pragma unroll
  for (int r = 0; r < 2; ++r)
    __builtin_amdgcn_global_load_lds(
        (const __attribute__((address_space(1))) void*)(g + r * 2048 + tid * 8),
        (__attribute__((address_space(3))) void*)(l + r * 2048 + tid * 8), 16, 0, 0);
}

#define WAITBAR(S)                                  \
  asm volatile(S ::: "memory");                     \
  __builtin_amdgcn_sched_barrier(0);                \
  __builtin_amdgcn_s_barrier();                     \
  __builtin_amdgcn_sched_barrier(0);

// one K-tile body: 12 ds_read_b128, 32 MFMA, 6 global_load_lds (2 tiles
// ahead). Relaxed interior (R6 structure — compiler pipelines reads with
// progressive lgkmcnt; fences proved harmful in R4/R7).
#define KTILE_BODY(DO_STAGE)                                                \
  {                                                                         \
    short8 aF[4], bF[4];                                                    \
    _Pragma("unroll")                                                       \
    for (int g = 0; g < 4; ++g)                                             \
      bF[g] = *reinterpret_cast<const short8*>(bC + g * 512);               \
    _Pragma("unroll")                                                       \
    for (int m4 = 0; m4 < 4; ++m4)                                          \
      aF[m4] = *reinterpret_cast<const short8*>(aC + m4 * 512);             \
    if (DO_STAGE) stageA(gAs, aN, tid);                                     \
    __builtin_amdgcn_s_setprio(1);                                          \
    _Pragma("unroll")                                                       \
    for (int m4 = 0; m4 < 4; ++m4)                                          \
      _Pragma("unroll")                                                     \
      for (int g = 0; g < 4; ++g)                                           \
        acc[m4][g] = __builtin_amdgcn_mfma_f32_16x16x32_bf16(               \
            aF[m4], bF[g], acc[m4][g], 0, 0, 0);                            \
    __builtin_amdgcn_s_setprio(0);                                          \
    _Pragma("unroll")                                                       \
    for (int m4 = 0; m4 < 4; ++m4)                                          \
      aF[m4] = *reinterpret_cast<const short8*>(aC + 2048 + m4 * 512);      \
    if (DO_STAGE) stageB(gBs, bN, tid);                                     \
    __builtin_amdgcn_s_setprio(1);                                          \
    _Pragma("unroll")                                                       \
    for (int m4 = 0; m4 < 4; ++m4)                                          \
      _Pragma("unroll")                                                     \
      for (int g = 0; g < 4; ++g)                                           \
        acc[4 + m4][g] = __builtin_amdgcn_mfma_f32_16x16x32_bf16(           \
            aF[m4], bF[g], acc[4 + m4][g], 0, 0, 0);                        \
    __builtin_amdgcn_s_setprio(0);                                          \
  }

// ---------------------------------------------------------------------------
// GEMM M=16384 Np=2048 K=1024. Tile 256x128, BK=32, 4 waves (2wr x 2wc),
// wave = 128x64 (16h x 4 gates), acc[8][4] = 128 AGPR (+ ~92 arch = 220
// -> 2 waves/SIMD per block). LDS ring-3 x 24KB = 72KB -> TWO blocks per CU:
// independent barriers, so one block's MFMA window covers the other's
// read/barrier window (cross-block pipe overlap; intra-block phase
// engineering failed in R4/R7). Depth-2 prefetch, one barrier per K-tile,
// steady-state counted vmcnt(6) (tile kt+2's 6 loads stay in flight).
// ---------------------------------------------------------------------------
__global__ __launch_bounds__(256, 2) void lstm_gemm_kernel(
    const unsigned short* __restrict__ Ap,
    const unsigned short* __restrict__ Bp,
    const float* __restrict__ z,
    const float* __restrict__ b_i, const float* __restrict__ b_f,
    const float* __restrict__ b_c, const float* __restrict__ b_o,
    float* __restrict__ out) {
  __shared__ unsigned short lds[36864];  // 72KB = 3 bufs x (A 16KB | B 8KB)

  int tid  = threadIdx.x;
  int bid  = blockIdx.x;
  int sw   = (bid & 7) * 128 + (bid >> 3);  // 1024 % 8 == 0 -> bijective
  int bn   = sw & 15;    // 16 N-tiles (32 h * 4 gates)
  int bm   = sw >> 4;    // 64 M-tiles
  int lane = tid & 63;
  int wid  = tid >> 6;   // 0..3
  int wr   = wid >> 1;   // 0..1 -> 128 rows
  int wc   = wid & 1;    // 0..1 -> 16 h * 4 gates

  floatx4 acc[8][4];
#pragma unroll
  for (int m = 0; m < 8; ++m)
#pragma unroll
    for (int g = 0; g < 4; ++g)
      acc[m][g] = (floatx4){0.f, 0.f, 0.f, 0.f};

  const unsigned short* gA = Ap + (uint64_t)bm * (32 * 8192);
  const unsigned short* gB = Bp + (uint64_t)bn * (32 * 4096);

  // prologue: stage tiles 0 (buf0) and 1 (buf1); wait tile0 -> vmcnt(6)
  stageA(gA, lds, tid);
  stageB(gB, lds + 8192, tid);
  stageA(gA + 8192, lds + 12288, tid);
  stageB(gB + 4096, lds + 12288 + 8192, tid);
  asm volatile("s_waitcnt vmcnt(6)" ::: "memory");
  __builtin_amdgcn_sched_barrier(0);
  __builtin_amdgcn_s_barrier();
  __builtin_amdgcn_sched_barrier(0);

  int cur = 0;
#pragma unroll 1
  for (int kt = 0; kt < 30; ++kt) {
    int nxt2 = (cur >= 1) ? cur - 1 : 2;  // (cur+2)%3
    const unsigned short* aC = lds + cur * 12288 + wr * 4096 + lane * 8;
    const unsigned short* bC = lds + cur * 12288 + 8192 + wc * 2048 + lane * 8;
    unsigned short* aN = lds + nxt2 * 12288;
    unsigned short* bN = aN + 8192;
    const unsigned short* gAs = gA + (kt + 2) * 8192;
    const unsigned short* gBs = gB + (kt + 2) * 4096;

    KTILE_BODY(true)
    WAITBAR("s_waitcnt vmcnt(6)")   // kt+1 landed; kt+2's 6 stay in flight
    cur = (cur == 2) ? 0 : cur + 1;
  }

  // tile 30: no staging; tile 31 must be fully landed
  {
    const unsigned short* aC = lds + cur * 12288 + wr * 4096 + lane * 8;
    const unsigned short* bC = lds + cur * 12288 + 8192 + wc * 2048 + lane * 8;
    unsigned short* aN = nullptr; unsigned short* bN = nullptr;
    const unsigned short* gAs = nullptr; const unsigned short* gBs = nullptr;
    KTILE_BODY(false)
    WAITBAR("s_waitcnt vmcnt(0)")
    cur = (cur == 2) ? 0 : cur + 1;
  }
  // tile 31: last, no barrier
  {
    const unsigned short* aC = lds + cur * 12288 + wr * 4096 + lane * 8;
    const unsigned short* bC = lds + cur * 12288 + 8192 + wc * 2048 + lane * 8;
    unsigned short* aN = nullptr; unsigned short* bN = nullptr;
    const unsigned short* gAs = nullptr; const unsigned short* gBs = nullptr;
    KTILE_BODY(false)
  }

  // ---- fused LSTM epilogue (lane-local: acc frag index g == gate)
  int h = bn * 32 + wc * 16 + (lane & 15);
  float vbi = b_i[h], vbf = b_f[h], vbc = b_c[h], vbo = b_o[h];
  int rbase = bm * 256 + wr * 128 + ((lane >> 4) << 2);
  float* outH = out;
  float* outC = out + (uint64_t)B_DIM * H_DIM;
#pragma unroll
  for (int m = 0; m < 8; ++m) {
#pragma unroll
    for (int j = 0; j < 4; ++j) {
      int r = rbase + m * 16 + j;
      float pi = acc[m][0][j] + vbi;
      float pf = acc[m][1][j] + vbf;
      float pc = acc[m][2][j] + vbc;
      float po = acc[m][3][j] + vbo;
      float gi = 1.f / (1.f + __expf(-pi));
      float gf = 1.f / (1.f + __expf(-pf));
      float gc = 1.f - 2.f / (__expf(2.f * pc) + 1.f);  // tanh
      float go = 1.f / (1.f + __expf(-po));
      float zv = z[(uint64_t)r * H_DIM + h];
      float cn = gf * zv + gi * gc;
      float hn = go * (1.f - 2.f / (__expf(2.f * cn) + 1.f));
      outH[(uint64_t)r * H_DIM + h] = hn;
      outC[(uint64_t)r * H_DIM + h] = cn;
    }
  }
}

extern "C" void kernel_launch(void* const* d_in, const int* in_sizes, int n_in,
                              void* d_out, int out_size, void* d_ws, size_t ws_size,
                              hipStream_t stream) {
  const float* z  = (const float*)d_in[0];
  const float* x  = (const float*)d_in[1];
  const float* Wi = (const float*)d_in[2];
  const float* Wf = (const float*)d_in[3];
  const float* Wc = (const float*)d_in[4];
  const float* Wo = (const float*)d_in[5];
  const float* bi = (const float*)d_in[6];
  const float* bf = (const float*)d_in[7];
  const float* bc = (const float*)d_in[8];
  const float* bo = (const float*)d_in[9];
  const float* Ui = (const float*)d_in[10];
  const float* Uf = (const float*)d_in[11];
  const float* Uc = (const float*)d_in[12];
  const float* Uo = (const float*)d_in[13];

  unsigned short* Ap = (unsigned short*)d_ws;                          // 32 MB
  unsigned short* Bp = (unsigned short*)((char*)d_ws
                        + (size_t)B_DIM * KTOT * sizeof(unsigned short)); // +4 MB
  float* out = (float*)d_out;

  hipLaunchKernelGGL(pack_w_kernel, dim3((size_t)NP * KTOT / 8 / 256), dim3(256), 0, stream,
                     Wi, Wf, Wc, Wo, Ui, Uf, Uc, Uo, Bp);
  hipLaunchKernelGGL(pack_a_kernel, dim3((size_t)B_DIM * KTOT / 8 / 256), dim3(256), 0, stream,
                     x, z, Ap);
  hipLaunchKernelGGL(lstm_gemm_kernel, dim3(1024), dim3(256), 0, stream,
                     Ap, Bp, z, bi, bf, bc, bo, out);
}